// Round 1
// baseline (148.615 us; speedup 1.0000x reference)
//
#include <hip/hip_runtime.h>
#include <hip/hip_bf16.h>

#define N_  16
#define L0_ 2048
#define L1_ 1024
#define D_  128
#define H_  384

// workspace layout (float element offsets)
#define PM1_0 0        // [8][16][128]
#define PM2_0 16384
#define PAM_0 32768    // int
#define PM1_1 49152    // [4][16][128]
#define PM2_1 57344
#define PAM_1 65536    // int
// total 73728 floats = 294912 bytes

typedef float  floatx4  __attribute__((ext_vector_type(4)));
typedef __bf16 bf16x8   __attribute__((ext_vector_type(8)));
typedef unsigned short ushortx8 __attribute__((ext_vector_type(8)));
typedef unsigned short ushortx4 __attribute__((ext_vector_type(4)));

__device__ __forceinline__ unsigned short f2bf(float f) {
  union { float f; unsigned int u; } v; v.f = f;
  unsigned int u = v.u;
  return (unsigned short)((u + 0x7fffu + ((u >> 16) & 1u)) >> 16);  // RNE
}

// ---------------------------------------------------------------------------
// Kernel 1: partial (top1, top2, argmax) per (tensor, n, d) over 256-row chunks
// grid: 128 blocks for x0 (16 n x 8 chunks) + 64 for x1 (16 n x 4 chunks)
// ---------------------------------------------------------------------------
__global__ __launch_bounds__(256) void stats_kernel(
    const float* __restrict__ x0, const float* __restrict__ x1,
    float* __restrict__ ws) {
  __shared__ float sm1[8][128];
  __shared__ float sm2[8][128];
  __shared__ int   sam[8][128];

  int bid = blockIdx.x;
  const float* x; int n, chunk, L; float *pm1, *pm2; int *pam;
  if (bid < 128) {
    x = x0; n = bid >> 3; chunk = bid & 7; L = L0_;
    pm1 = ws + PM1_0; pm2 = ws + PM2_0; pam = (int*)(ws + PAM_0);
  } else {
    int b = bid - 128;
    x = x1; n = b >> 2; chunk = b & 3; L = L1_;
    pm1 = ws + PM1_1; pm2 = ws + PM2_1; pam = (int*)(ws + PAM_1);
  }

  int tid = threadIdx.x;
  int q = tid & 31, sub = tid >> 5;          // q: float4 column group, sub: row slice
  int lbase = chunk * 256 + sub * 32;
  const float* xp = x + (size_t)(n * L + lbase) * D_ + q * 4;

  float m1[4], m2[4]; int am[4];
#pragma unroll
  for (int j = 0; j < 4; j++) { m1[j] = -3.4e38f; m2[j] = -3.4e38f; am[j] = 0; }

  for (int r = 0; r < 32; r++) {
    float4 v = *(const float4*)(xp + (size_t)r * D_);
    float vv[4] = { v.x, v.y, v.z, v.w };
    int l = lbase + r;
#pragma unroll
    for (int j = 0; j < 4; j++) {
      if (vv[j] > m1[j]) { m2[j] = m1[j]; m1[j] = vv[j]; am[j] = l; }
      else if (vv[j] > m2[j]) m2[j] = vv[j];
    }
  }
#pragma unroll
  for (int j = 0; j < 4; j++) {
    int d = q * 4 + j;
    sm1[sub][d] = m1[j]; sm2[sub][d] = m2[j]; sam[sub][d] = am[j];
  }
  __syncthreads();

  if (tid < 128) {
    int d = tid;
    float M1 = sm1[0][d], M2 = sm2[0][d]; int AM = sam[0][d];
    for (int s = 1; s < 8; s++) {
      float c1 = sm1[s][d];
      if (c1 > M1) { M2 = fmaxf(M1, sm2[s][d]); M1 = c1; AM = sam[s][d]; }
      else M2 = fmaxf(M2, c1);
    }
    int idx = (chunk * N_ + n) * D_ + d;
    pm1[idx] = M1; pm2[idx] = M2; pam[idx] = AM;
  }
}

// ---------------------------------------------------------------------------
// Kernel 2: fused merge + base GEMV + bf16 MFMA GEMM + sparse LOO corrections
// grid: 256 blocks (group0: 16 n x 16 row-tiles) + 128 (group1: 16 n x 8)
// block tile: 128 rows x 128 cols, K=128; 4 waves, each 64x64 (4x4 of 16x16x32)
// ---------------------------------------------------------------------------
__global__ __launch_bounds__(256) void fused_gemm_kernel(
    const float* __restrict__ x0, const float* __restrict__ x1,
    const float* __restrict__ W0, const float* __restrict__ b0,
    const float* __restrict__ W1, const float* __restrict__ b1,
    float* __restrict__ out, float* __restrict__ ws) {
  __shared__ unsigned short xs[128 * 136];   // x tile, bf16, +8 pad per row
  __shared__ unsigned short wsm[128 * 136];  // W[:,0:128], bf16 [o][k]
  __shared__ float t1a[128], t1b[128], sdelta[128], sbase[128], bpart[128];
  __shared__ int   samax[128];
  __shared__ int   hitcnt;
  __shared__ int   hitrow[128]; __shared__ int hitd[128]; __shared__ float hitdelta[128];

  int bid = blockIdx.x;
  int g, n, r0, L;
  const float *x, *W, *bias; float* y;
  if (bid < 256) { g = 0; n = bid >> 4; r0 = (bid & 15) << 7; L = L0_; x = x0; W = W0; bias = b0; y = out; }
  else { int b = bid - 256; g = 1; n = b >> 3; r0 = (b & 7) << 7; L = L1_; x = x1; W = W1; bias = b1; y = out + (size_t)N_ * L0_ * D_; }

  int tid = threadIdx.x;
  if (tid == 0) hitcnt = 0;

  // --- stage W[:,0:128] and x tile into LDS as bf16 ---
  const float* xt = x + (size_t)(n * L + r0) * D_;
#pragma unroll
  for (int i = 0; i < 16; i++) {
    int f = tid + 256 * i;
    int row = f >> 5, c4 = f & 31;
    float4 wv = *(const float4*)(W + (size_t)row * H_ + c4 * 4);
    ushortx4 wp = { f2bf(wv.x), f2bf(wv.y), f2bf(wv.z), f2bf(wv.w) };
    *(ushortx4*)&wsm[row * 136 + c4 * 4] = wp;
    float4 xv = *(const float4*)(xt + (size_t)row * D_ + c4 * 4);
    ushortx4 xq = { f2bf(xv.x), f2bf(xv.y), f2bf(xv.z), f2bf(xv.w) };
    *(ushortx4*)&xs[row * 136 + c4 * 4] = xq;
  }

  // --- merge partial stats for this n (both tensors) ---
  if (tid < 128) {
    int d = tid;
    const float* pm1 = ws + PM1_0; const float* pm2 = ws + PM2_0;
    const int* pam = (const int*)(ws + PAM_0);
    int idx = n * D_ + d;
    float M1 = pm1[idx], M2 = pm2[idx]; int AM = pam[idx];
    for (int c = 1; c < 8; c++) {
      int id2 = (c * N_ + n) * D_ + d;
      float c1 = pm1[id2];
      if (c1 > M1) { M2 = fmaxf(M1, pm2[id2]); M1 = c1; AM = pam[id2]; }
      else M2 = fmaxf(M2, c1);
    }
    t1a[d] = M1;
    if (g == 0) { sdelta[d] = M2 - M1; samax[d] = AM; }
  } else {
    int d = tid - 128;
    const float* pm1 = ws + PM1_1; const float* pm2 = ws + PM2_1;
    const int* pam = (const int*)(ws + PAM_1);
    int idx = n * D_ + d;
    float M1 = pm1[idx], M2 = pm2[idx]; int AM = pam[idx];
    for (int c = 1; c < 4; c++) {
      int id2 = (c * N_ + n) * D_ + d;
      float c1 = pm1[id2];
      if (c1 > M1) { M2 = fmaxf(M1, pm2[id2]); M1 = c1; AM = pam[id2]; }
      else M2 = fmaxf(M2, c1);
    }
    t1b[d] = M1;
    if (g == 1) { sdelta[d] = M2 - M1; samax[d] = AM; }
  }
  __syncthreads();

  // --- base[n,o] = bias[o] + t1a . W[o,128:256] + t1b . W[o,256:384] ---
  int o = tid & 127, hhalf = tid >> 7;
  float bsum = 0.f;
  {
    const float* wr = W + (size_t)o * H_ + 128 + hhalf * 128;
    const float* tv = hhalf ? t1b : t1a;
#pragma unroll 4
    for (int d = 0; d < 128; d += 4) {
      float4 wv = *(const float4*)(wr + d);
      bsum += tv[d] * wv.x + tv[d + 1] * wv.y + tv[d + 2] * wv.z + tv[d + 3] * wv.w;
    }
    if (hhalf) bpart[o] = bsum;
  }
  // --- hit detection: corrections landing in this row tile ---
  if (tid < 128) {
    int d = tid; int am = samax[d]; float dl = sdelta[d];
    if (am >= r0 && am < r0 + 128 && dl != 0.f) {
      int k = atomicAdd(&hitcnt, 1);
      hitrow[k] = am - r0; hitd[k] = d; hitdelta[k] = dl;
    }
  }
  __syncthreads();
  if (tid < 128) sbase[tid] = bias[tid] + bsum + bpart[tid];
  __syncthreads();

  // --- MFMA main loop ---
  int w = tid >> 6, lane = tid & 63;
  int rw = (w >> 1) << 6, cw = (w & 1) << 6;
  int lm = lane & 15, lq = lane >> 4;
  floatx4 acc[4][4];
#pragma unroll
  for (int i = 0; i < 4; i++)
#pragma unroll
    for (int j = 0; j < 4; j++) acc[i][j] = (floatx4){0.f, 0.f, 0.f, 0.f};

#pragma unroll
  for (int kk = 0; kk < 4; kk++) {
    int ko = kk * 32 + lq * 8;
    bf16x8 af[4], bfr[4];
#pragma unroll
    for (int i = 0; i < 4; i++)
      af[i] = __builtin_bit_cast(bf16x8, *(const ushortx8*)&xs[(rw + i * 16 + lm) * 136 + ko]);
#pragma unroll
    for (int j = 0; j < 4; j++)
      bfr[j] = __builtin_bit_cast(bf16x8, *(const ushortx8*)&wsm[(cw + j * 16 + lm) * 136 + ko]);
#pragma unroll
    for (int i = 0; i < 4; i++)
#pragma unroll
      for (int j = 0; j < 4; j++)
        acc[i][j] = __builtin_amdgcn_mfma_f32_16x16x32_bf16(af[i], bfr[j], acc[i][j], 0, 0, 0);
  }

  // --- apply sparse LOO corrections (fp32, exact) ---
  int hc = hitcnt;
  int offg = 128 + (g << 7);   // group0 -> W[:,128+d], group1 -> W[:,256+d]
#pragma unroll
  for (int i = 0; i < 4; i++) {
#pragma unroll
    for (int r = 0; r < 4; r++) {
      int row = rw + i * 16 + lq * 4 + r;
      for (int k = 0; k < hc; k++) {
        if (hitrow[k] == row) {
          float dl = hitdelta[k];
          const float* wp = W + offg + hitd[k];
#pragma unroll
          for (int j = 0; j < 4; j++) {
            int col = cw + j * 16 + lm;
            acc[i][j][r] += dl * wp[(size_t)col * H_];
          }
        }
      }
    }
  }

  // --- store ---
  float* yb = y + (size_t)(n * L + r0) * D_;
#pragma unroll
  for (int i = 0; i < 4; i++)
#pragma unroll
    for (int j = 0; j < 4; j++) {
      int col = cw + j * 16 + lm;
      float bb = sbase[col];
#pragma unroll
      for (int r = 0; r < 4; r++) {
        int row = rw + i * 16 + lq * 4 + r;
        yb[(size_t)row * D_ + col] = acc[i][j][r] + bb;
      }
    }
}

extern "C" void kernel_launch(void* const* d_in, const int* in_sizes, int n_in,
                              void* d_out, int out_size, void* d_ws, size_t ws_size,
                              hipStream_t stream) {
  const float* x0 = (const float*)d_in[0];
  const float* x1 = (const float*)d_in[1];
  const float* W0 = (const float*)d_in[2];
  const float* b0 = (const float*)d_in[3];
  const float* W1 = (const float*)d_in[4];
  const float* b1 = (const float*)d_in[5];
  float* out = (float*)d_out;
  float* ws  = (float*)d_ws;

  hipLaunchKernelGGL(stats_kernel, dim3(192), dim3(256), 0, stream, x0, x1, ws);
  hipLaunchKernelGGL(fused_gemm_kernel, dim3(384), dim3(256), 0, stream,
                     x0, x1, W0, b0, W1, b1, out, ws);
}

// Round 2
// 143.554 us; speedup vs baseline: 1.0353x; 1.0353x over previous
//
#include <hip/hip_runtime.h>
#include <hip/hip_bf16.h>

#define N_  16
#define L0_ 2048
#define L1_ 1024
#define D_  128
#define H_  384

// workspace layout (4-byte element offsets)
#define PM1_0 0        // float [32][16][128]
#define PM2_0 65536
#define PAM_0 131072   // int
#define PM1_1 196608   // float [16][16][128]
#define PM2_1 229376
#define PAM_1 262144   // int
#define BASE_ 294912   // float [2][16][128]
#define WBF_  299008   // bf16 [2][128][128] (32768 shorts = 16384 words)
#define HCNT_ 315392   // int [768]
#define HLIST_ 316160  // int [768][128][2]
// end: 512768 words ~= 2.05 MB

typedef float  floatx4  __attribute__((ext_vector_type(4)));
typedef __bf16 bf16x8   __attribute__((ext_vector_type(8)));
typedef unsigned short ushortx8 __attribute__((ext_vector_type(8)));

__device__ __forceinline__ unsigned short f2bf(float f) {
  union { float f; unsigned int u; } v; v.f = f;
  unsigned int u = v.u;
  return (unsigned short)((u + 0x7fffu + ((u >> 16) & 1u)) >> 16);  // RNE
}

// ---------------------------------------------------------------------------
// Kernel 1: partial (top1, top2, argmax) per (tensor, n, d) over 64-row chunks
// grid 768: x0 -> 512 blocks (16 n x 32 chunks), x1 -> 256 (16 n x 16 chunks)
// ---------------------------------------------------------------------------
__global__ __launch_bounds__(256) void stats_kernel(
    const float* __restrict__ x0, const float* __restrict__ x1,
    float* __restrict__ ws) {
  __shared__ float sm1[8][128], sm2[8][128];
  __shared__ int   sam[8][128];
  int bid = blockIdx.x, tid = threadIdx.x;
  const float* x; int n, chunk, L; float *pm1, *pm2; int* pam;
  if (bid < 512) {
    x = x0; n = bid >> 5; chunk = bid & 31; L = L0_;
    pm1 = ws + PM1_0; pm2 = ws + PM2_0; pam = (int*)ws + PAM_0;
  } else {
    int b = bid - 512;
    x = x1; n = b >> 4; chunk = b & 15; L = L1_;
    pm1 = ws + PM1_1; pm2 = ws + PM2_1; pam = (int*)ws + PAM_1;
  }
  int q = tid & 31, sub = tid >> 5;          // q: float4 col group, sub: 8-row slice
  int lbase = chunk * 64 + sub * 8;
  const float* xp = x + (size_t)(n * L + lbase) * D_ + q * 4;

  float m1[4], m2[4]; int am[4];
#pragma unroll
  for (int j = 0; j < 4; j++) { m1[j] = -3.4e38f; m2[j] = -3.4e38f; am[j] = 0; }
#pragma unroll
  for (int r = 0; r < 8; r++) {
    float4 v = *(const float4*)(xp + (size_t)r * D_);
    float vv[4] = { v.x, v.y, v.z, v.w };
    int l = lbase + r;
#pragma unroll
    for (int j = 0; j < 4; j++) {
      if (vv[j] > m1[j]) { m2[j] = m1[j]; m1[j] = vv[j]; am[j] = l; }
      else if (vv[j] > m2[j]) m2[j] = vv[j];
    }
  }
#pragma unroll
  for (int j = 0; j < 4; j++) {
    int d = q * 4 + j;
    sm1[sub][d] = m1[j]; sm2[sub][d] = m2[j]; sam[sub][d] = am[j];
  }
  __syncthreads();
  if (tid < 128) {
    int d = tid;
    float M1 = sm1[0][d], M2 = sm2[0][d]; int AM = sam[0][d];
#pragma unroll
    for (int s = 1; s < 8; s++) {
      float c1 = sm1[s][d];
      if (c1 > M1) { M2 = fmaxf(M1, sm2[s][d]); M1 = c1; AM = sam[s][d]; }
      else M2 = fmaxf(M2, c1);
    }
    int idx = (chunk * N_ + n) * D_ + d;
    pm1[idx] = M1; pm2[idx] = M2; pam[idx] = AM;
  }
}

// ---------------------------------------------------------------------------
// Kernel 2: per-(g,n) prep — merge partials, base GEMV, per-tile hit lists,
// bf16 W conversion. grid 32 (g*16+n), 256 threads.
// ---------------------------------------------------------------------------
__global__ __launch_bounds__(256) void prep_kernel(
    const float* __restrict__ W0, const float* __restrict__ b0,
    const float* __restrict__ W1, const float* __restrict__ b1,
    float* __restrict__ ws) {
  __shared__ float t1a[128], t1b[128], sdl[128], bpart[128];
  __shared__ int   sam2[128], scnt[32];
  int bid = blockIdx.x, tid = threadIdx.x;
  int g = bid >> 4, n = bid & 15;
  const float* W = g ? W1 : W0;
  const float* bias = g ? b1 : b0;

  if (tid < 32) scnt[tid] = 0;

  if (tid < 128) {        // merge x0 partials (32 chunks)
    int d = tid;
    const float* pm1 = ws + PM1_0; const float* pm2 = ws + PM2_0;
    const int* pam = (int*)ws + PAM_0;
    float M1 = pm1[n * D_ + d], M2 = pm2[n * D_ + d]; int AM = pam[n * D_ + d];
    for (int c = 1; c < 32; c++) {
      int id2 = (c * N_ + n) * D_ + d;
      float c1 = pm1[id2];
      if (c1 > M1) { M2 = fmaxf(M1, pm2[id2]); M1 = c1; AM = pam[id2]; }
      else M2 = fmaxf(M2, c1);
    }
    t1a[d] = M1;
    if (g == 0) { sdl[d] = M2 - M1; sam2[d] = AM; }
  } else {                // merge x1 partials (16 chunks)
    int d = tid - 128;
    const float* pm1 = ws + PM1_1; const float* pm2 = ws + PM2_1;
    const int* pam = (int*)ws + PAM_1;
    float M1 = pm1[n * D_ + d], M2 = pm2[n * D_ + d]; int AM = pam[n * D_ + d];
    for (int c = 1; c < 16; c++) {
      int id2 = (c * N_ + n) * D_ + d;
      float c1 = pm1[id2];
      if (c1 > M1) { M2 = fmaxf(M1, pm2[id2]); M1 = c1; AM = pam[id2]; }
      else M2 = fmaxf(M2, c1);
    }
    t1b[d] = M1;
    if (g == 1) { sdl[d] = M2 - M1; sam2[d] = AM; }
  }
  __syncthreads();

  // base[g][n][o] = bias[o] + t1a.W[o,128:256] + t1b.W[o,256:384]
  int o = tid & 127, half = tid >> 7;
  {
    const float* wr = W + (size_t)o * H_ + 128 + half * 128;
    const float* tv = half ? t1b : t1a;
    float bsum = 0.f;
#pragma unroll 4
    for (int d = 0; d < 128; d += 4) {
      float4 wv = *(const float4*)(wr + d);
      bsum += tv[d] * wv.x + tv[d + 1] * wv.y + tv[d + 2] * wv.z + tv[d + 3] * wv.w;
    }
    if (half) { bpart[o] = bsum; }
    __syncthreads();
    if (!half) ws[BASE_ + (g * N_ + n) * D_ + o] = bias[o] + bsum + bpart[o];
  }

  // scatter LOO corrections into per-64-row-tile lists
  if (tid < 128) {
    int d = tid; int am = sam2[d]; float dl = sdl[d];
    int t = am >> 6;
    int slot = atomicAdd(&scnt[t], 1);
    int tile = (g == 0) ? (n * 32 + t) : (512 + n * 16 + t);
    int* hl = (int*)ws + HLIST_ + tile * 256;
    hl[slot * 2]     = (am & 63) | (d << 8);
    hl[slot * 2 + 1] = __float_as_int(dl);
  }
  __syncthreads();
  int tcount = g ? 16 : 32;
  if (tid < tcount) {
    int tile = (g == 0) ? (n * 32 + tid) : (512 + n * 16 + tid);
    ((int*)ws)[HCNT_ + tile] = scnt[tid];
  }

  // bf16 conversion of W[:,0:128] (once per g)
  if (n == 0) {
    unsigned short* wbf = (unsigned short*)(ws + WBF_) + g * 16384;
#pragma unroll
    for (int it = 0; it < 64; it++) {
      int f = tid + 256 * it;
      int oo = f >> 7, k = f & 127;
      wbf[f] = f2bf(W[(size_t)oo * H_ + k]);
    }
  }
}

// ---------------------------------------------------------------------------
// Kernel 3: GEMM, no LDS, no barriers. grid 768 (64-row tiles), 4 waves/block,
// each wave 32 rows x 64 cols (2x4 of 16x16x32 bf16 MFMA).
// ---------------------------------------------------------------------------
__global__ __launch_bounds__(256) void gemm_kernel(
    const float* __restrict__ x0, const float* __restrict__ x1,
    const float* __restrict__ W0, const float* __restrict__ W1,
    float* __restrict__ out, const float* __restrict__ ws) {
  int bid = blockIdx.x, tid = threadIdx.x;
  int g, n, r0, L; const float *x, *W; float* y;
  if (bid < 512) { g = 0; n = bid >> 5; r0 = (bid & 31) << 6; L = L0_; x = x0; W = W0; y = out; }
  else { int b = bid - 512; g = 1; n = b >> 4; r0 = (b & 15) << 6; L = L1_; x = x1; W = W1;
         y = out + (size_t)N_ * L0_ * D_; }

  int w = tid >> 6, lane = tid & 63, lm = lane & 15, lq = lane >> 4;
  int rsub = (w & 1) << 5, cw = (w >> 1) << 6;

  // B fragments straight from prepacked bf16 W (L2-resident)
  const unsigned short* wbf = (const unsigned short*)(ws + WBF_) + g * 16384;
  bf16x8 bfr[4][4];
#pragma unroll
  for (int j = 0; j < 4; j++)
#pragma unroll
    for (int kk = 0; kk < 4; kk++)
      bfr[j][kk] = __builtin_bit_cast(bf16x8,
          *(const ushortx8*)&wbf[(cw + j * 16 + lm) * 128 + kk * 32 + lq * 8]);

  // A fragments straight from x (fp32, L3-warm), converted in-register
  const float* xb = x + (size_t)(n * L + r0 + rsub) * D_;
  bf16x8 af[2][4];
#pragma unroll
  for (int i = 0; i < 2; i++)
#pragma unroll
    for (int kk = 0; kk < 4; kk++) {
      const float* p = xb + (size_t)(i * 16 + lm) * D_ + kk * 32 + lq * 8;
      float4 u = *(const float4*)p;
      float4 v = *(const float4*)(p + 4);
      ushortx8 t = { f2bf(u.x), f2bf(u.y), f2bf(u.z), f2bf(u.w),
                     f2bf(v.x), f2bf(v.y), f2bf(v.z), f2bf(v.w) };
      af[i][kk] = __builtin_bit_cast(bf16x8, t);
    }

  floatx4 acc[2][4];
#pragma unroll
  for (int i = 0; i < 2; i++)
#pragma unroll
    for (int j = 0; j < 4; j++) acc[i][j] = (floatx4){0.f, 0.f, 0.f, 0.f};
#pragma unroll
  for (int kk = 0; kk < 4; kk++)
#pragma unroll
    for (int i = 0; i < 2; i++)
#pragma unroll
      for (int j = 0; j < 4; j++)
        acc[i][j] = __builtin_amdgcn_mfma_f32_16x16x32_bf16(af[i][kk], bfr[j][kk], acc[i][j], 0, 0, 0);

  // sparse LOO corrections (fp32-exact)
  int hc = ((const int*)ws)[HCNT_ + bid];
  const int* hl = (const int*)ws + HLIST_ + bid * 256;
  int off = 128 + (g << 7);
  for (int k = 0; k < hc; k++) {
    int e = hl[2 * k]; float dl = __int_as_float(hl[2 * k + 1]);
    int row = e & 63, d = e >> 8;
    int rl = row - rsub;
    if (rl >= 0 && rl < 32 && ((rl >> 2) & 3) == lq) {
      int i = rl >> 4, rr = rl & 3;
#pragma unroll
      for (int j = 0; j < 4; j++)
        acc[i][j][rr] += dl * W[(size_t)(cw + j * 16 + lm) * H_ + off + d];
    }
  }

  // base + store
  const float* bp = ws + BASE_ + (g * N_ + n) * D_;
  float bb[4];
#pragma unroll
  for (int j = 0; j < 4; j++) bb[j] = bp[cw + j * 16 + lm];
  float* yb = y + (size_t)(n * L + r0 + rsub) * D_;
#pragma unroll
  for (int i = 0; i < 2; i++)
#pragma unroll
    for (int j = 0; j < 4; j++)
#pragma unroll
      for (int r = 0; r < 4; r++)
        yb[(size_t)(i * 16 + lq * 4 + r) * D_ + cw + j * 16 + lm] = acc[i][j][r] + bb[j];
}

extern "C" void kernel_launch(void* const* d_in, const int* in_sizes, int n_in,
                              void* d_out, int out_size, void* d_ws, size_t ws_size,
                              hipStream_t stream) {
  const float* x0 = (const float*)d_in[0];
  const float* x1 = (const float*)d_in[1];
  const float* W0 = (const float*)d_in[2];
  const float* b0 = (const float*)d_in[3];
  const float* W1 = (const float*)d_in[4];
  const float* b1 = (const float*)d_in[5];
  float* out = (float*)d_out;
  float* ws  = (float*)d_ws;

  hipLaunchKernelGGL(stats_kernel, dim3(768), dim3(256), 0, stream, x0, x1, ws);
  hipLaunchKernelGGL(prep_kernel,  dim3(32),  dim3(256), 0, stream, W0, b0, W1, b1, ws);
  hipLaunchKernelGGL(gemm_kernel,  dim3(768), dim3(256), 0, stream,
                     x0, x1, W0, W1, out, ws);
}

// Round 3
// 136.991 us; speedup vs baseline: 1.0849x; 1.0479x over previous
//
#include <hip/hip_runtime.h>
#include <hip/hip_bf16.h>

#define N_  16
#define L0_ 2048
#define L1_ 1024
#define D_  128
#define H_  384

// workspace layout (4-byte element offsets)
#define PM1_0 0        // float [32][16][128]
#define PM2_0 65536
#define PAM_0 131072   // int
#define PM1_1 196608   // float [16][16][128]
#define PM2_1 229376
#define PAM_1 262144   // int
#define BASE_ 294912   // float [2][16][128]
#define WBF_  299008   // bf16 [2][128][128] (32768 shorts = 16384 words)
#define HCNT_ 315392   // int [768]
#define HLIST_ 316160  // int [768][128][2]

typedef float  floatx4  __attribute__((ext_vector_type(4)));
typedef __bf16 bf16x8   __attribute__((ext_vector_type(8)));
typedef unsigned short ushortx8 __attribute__((ext_vector_type(8)));

__device__ __forceinline__ unsigned short f2bf(float f) {
  union { float f; unsigned int u; } v; v.f = f;
  unsigned int u = v.u;
  return (unsigned short)((u + 0x7fffu + ((u >> 16) & 1u)) >> 16);  // RNE
}

// ---------------------------------------------------------------------------
// Kernel 1: partial (top1, top2, argmax) per (tensor, n, d) over 64-row chunks
// grid 768: x0 -> 512 blocks (16 n x 32 chunks), x1 -> 256 (16 n x 16 chunks)
// ---------------------------------------------------------------------------
__global__ __launch_bounds__(256) void stats_kernel(
    const float* __restrict__ x0, const float* __restrict__ x1,
    float* __restrict__ ws) {
  __shared__ float sm1[8][128], sm2[8][128];
  __shared__ int   sam[8][128];
  int bid = blockIdx.x, tid = threadIdx.x;
  const float* x; int n, chunk, L; float *pm1, *pm2; int* pam;
  if (bid < 512) {
    x = x0; n = bid >> 5; chunk = bid & 31; L = L0_;
    pm1 = ws + PM1_0; pm2 = ws + PM2_0; pam = (int*)ws + PAM_0;
  } else {
    int b = bid - 512;
    x = x1; n = b >> 4; chunk = b & 15; L = L1_;
    pm1 = ws + PM1_1; pm2 = ws + PM2_1; pam = (int*)ws + PAM_1;
  }
  int q = tid & 31, sub = tid >> 5;
  int lbase = chunk * 64 + sub * 8;
  const float* xp = x + (size_t)(n * L + lbase) * D_ + q * 4;

  float m1[4], m2[4]; int am[4];
#pragma unroll
  for (int j = 0; j < 4; j++) { m1[j] = -3.4e38f; m2[j] = -3.4e38f; am[j] = 0; }
#pragma unroll
  for (int r = 0; r < 8; r++) {
    float4 v = *(const float4*)(xp + (size_t)r * D_);
    float vv[4] = { v.x, v.y, v.z, v.w };
    int l = lbase + r;
#pragma unroll
    for (int j = 0; j < 4; j++) {
      if (vv[j] > m1[j]) { m2[j] = m1[j]; m1[j] = vv[j]; am[j] = l; }
      else if (vv[j] > m2[j]) m2[j] = vv[j];
    }
  }
#pragma unroll
  for (int j = 0; j < 4; j++) {
    int d = q * 4 + j;
    sm1[sub][d] = m1[j]; sm2[sub][d] = m2[j]; sam[sub][d] = am[j];
  }
  __syncthreads();
  if (tid < 128) {
    int d = tid;
    float M1 = sm1[0][d], M2 = sm2[0][d]; int AM = sam[0][d];
#pragma unroll
    for (int s = 1; s < 8; s++) {
      float c1 = sm1[s][d];
      if (c1 > M1) { M2 = fmaxf(M1, sm2[s][d]); M1 = c1; AM = sam[s][d]; }
      else M2 = fmaxf(M2, c1);
    }
    int idx = (chunk * N_ + n) * D_ + d;
    pm1[idx] = M1; pm2[idx] = M2; pam[idx] = AM;
  }
}

// ---------------------------------------------------------------------------
// Kernel 2: per-(g,n) prep — merge partials, base GEMV, per-tile hit lists,
// bf16 W conversion. grid 32 (g*16+n), 256 threads.
// ---------------------------------------------------------------------------
__global__ __launch_bounds__(256) void prep_kernel(
    const float* __restrict__ W0, const float* __restrict__ b0,
    const float* __restrict__ W1, const float* __restrict__ b1,
    float* __restrict__ ws) {
  __shared__ float t1a[128], t1b[128], sdl[128], bpart[128];
  __shared__ int   sam2[128], scnt[32];
  int bid = blockIdx.x, tid = threadIdx.x;
  int g = bid >> 4, n = bid & 15;
  const float* W = g ? W1 : W0;
  const float* bias = g ? b1 : b0;

  if (tid < 32) scnt[tid] = 0;

  if (tid < 128) {        // merge x0 partials (32 chunks)
    int d = tid;
    const float* pm1 = ws + PM1_0; const float* pm2 = ws + PM2_0;
    const int* pam = (int*)ws + PAM_0;
    float M1 = pm1[n * D_ + d], M2 = pm2[n * D_ + d]; int AM = pam[n * D_ + d];
    for (int c = 1; c < 32; c++) {
      int id2 = (c * N_ + n) * D_ + d;
      float c1 = pm1[id2];
      if (c1 > M1) { M2 = fmaxf(M1, pm2[id2]); M1 = c1; AM = pam[id2]; }
      else M2 = fmaxf(M2, c1);
    }
    t1a[d] = M1;
    if (g == 0) { sdl[d] = M2 - M1; sam2[d] = AM; }
  } else {                // merge x1 partials (16 chunks)
    int d = tid - 128;
    const float* pm1 = ws + PM1_1; const float* pm2 = ws + PM2_1;
    const int* pam = (int*)ws + PAM_1;
    float M1 = pm1[n * D_ + d], M2 = pm2[n * D_ + d]; int AM = pam[n * D_ + d];
    for (int c = 1; c < 16; c++) {
      int id2 = (c * N_ + n) * D_ + d;
      float c1 = pm1[id2];
      if (c1 > M1) { M2 = fmaxf(M1, pm2[id2]); M1 = c1; AM = pam[id2]; }
      else M2 = fmaxf(M2, c1);
    }
    t1b[d] = M1;
    if (g == 1) { sdl[d] = M2 - M1; sam2[d] = AM; }
  }
  __syncthreads();

  // base[g][n][o] = bias[o] + t1a.W[o,128:256] + t1b.W[o,256:384]
  int o = tid & 127, half = tid >> 7;
  {
    const float* wr = W + (size_t)o * H_ + 128 + half * 128;
    const float* tv = half ? t1b : t1a;
    float bsum = 0.f;
#pragma unroll 4
    for (int d = 0; d < 128; d += 4) {
      float4 wv = *(const float4*)(wr + d);
      bsum += tv[d] * wv.x + tv[d + 1] * wv.y + tv[d + 2] * wv.z + tv[d + 3] * wv.w;
    }
    if (half) { bpart[o] = bsum; }
    __syncthreads();
    if (!half) ws[BASE_ + (g * N_ + n) * D_ + o] = bias[o] + bsum + bpart[o];
  }

  // scatter LOO corrections into per-64-row-tile lists
  if (tid < 128) {
    int d = tid; int am = sam2[d]; float dl = sdl[d];
    int t = am >> 6;
    int slot = atomicAdd(&scnt[t], 1);
    int tile = (g == 0) ? (n * 32 + t) : (512 + n * 16 + t);
    int* hl = (int*)ws + HLIST_ + tile * 256;
    hl[slot * 2]     = (am & 63) | (d << 8);
    hl[slot * 2 + 1] = __float_as_int(dl);
  }
  __syncthreads();
  int tcount = g ? 16 : 32;
  if (tid < tcount) {
    int tile = (g == 0) ? (n * 32 + tid) : (512 + n * 16 + tid);
    ((int*)ws)[HCNT_ + tile] = scnt[tid];
  }

  // bf16 conversion of W[:,0:128] (once per g)
  if (n == 0) {
    unsigned short* wbf = (unsigned short*)(ws + WBF_) + g * 16384;
#pragma unroll
    for (int it = 0; it < 64; it++) {
      int f = tid + 256 * it;
      int oo = f >> 7, k = f & 127;
      wbf[f] = f2bf(W[(size_t)oo * H_ + k]);
    }
  }
}

// ---------------------------------------------------------------------------
// Kernel 3: GEMM, no LDS, no barriers. grid 768 (64-row tiles), 4 waves/block.
// Wave: 32 rows x 64 cols. K-loop NOT unrolled -> live VGPRs ~80, no spill.
// B fragments re-read per k-step from 64KB L2-resident prepacked bf16 W.
// ---------------------------------------------------------------------------
__global__ __launch_bounds__(256) void gemm_kernel(
    const float* __restrict__ x0, const float* __restrict__ x1,
    const float* __restrict__ W0, const float* __restrict__ W1,
    float* __restrict__ out, const float* __restrict__ ws) {
  int bid = blockIdx.x, tid = threadIdx.x;
  int g, n, r0, L; const float *x, *W; float* y;
  if (bid < 512) { g = 0; n = bid >> 5; r0 = (bid & 31) << 6; L = L0_; x = x0; W = W0; y = out; }
  else { int b = bid - 512; g = 1; n = b >> 4; r0 = (b & 15) << 6; L = L1_; x = x1; W = W1;
         y = out + (size_t)N_ * L0_ * D_; }

  int w = tid >> 6, lane = tid & 63, lm = lane & 15, lq = lane >> 4;
  int rsub = (w & 1) << 5, cw = (w >> 1) << 6;

  // hoist scalars that overlap the MFMA loop
  int hc = ((const int*)ws)[HCNT_ + bid];
  const int* hl = (const int*)ws + HLIST_ + bid * 256;
  const float* bp = ws + BASE_ + (g * N_ + n) * D_;
  float bb[4];
#pragma unroll
  for (int j = 0; j < 4; j++) bb[j] = bp[cw + j * 16 + lm];

  const unsigned short* wbf = (const unsigned short*)(ws + WBF_) + g * 16384;
  const float* xb = x + (size_t)(n * L + r0 + rsub) * D_;

  floatx4 acc[2][4];
#pragma unroll
  for (int i = 0; i < 2; i++)
#pragma unroll
    for (int j = 0; j < 4; j++) acc[i][j] = (floatx4){0.f, 0.f, 0.f, 0.f};

#pragma unroll 1
  for (int kk = 0; kk < 4; kk++) {
    int ko = kk * 32 + lq * 8;
    bf16x8 af[2];
#pragma unroll
    for (int i = 0; i < 2; i++) {
      const float* p = xb + (size_t)(i * 16 + lm) * D_ + ko;
      float4 u = *(const float4*)p;
      float4 v = *(const float4*)(p + 4);
      ushortx8 t = { f2bf(u.x), f2bf(u.y), f2bf(u.z), f2bf(u.w),
                     f2bf(v.x), f2bf(v.y), f2bf(v.z), f2bf(v.w) };
      af[i] = __builtin_bit_cast(bf16x8, t);
    }
    bf16x8 bfr[4];
#pragma unroll
    for (int j = 0; j < 4; j++)
      bfr[j] = __builtin_bit_cast(bf16x8,
          *(const ushortx8*)&wbf[(cw + j * 16 + lm) * 128 + ko]);
#pragma unroll
    for (int i = 0; i < 2; i++)
#pragma unroll
      for (int j = 0; j < 4; j++)
        acc[i][j] = __builtin_amdgcn_mfma_f32_16x16x32_bf16(af[i], bfr[j], acc[i][j], 0, 0, 0);
  }

  // sparse LOO corrections (fp32-exact)
  int off = 128 + (g << 7);
  for (int k = 0; k < hc; k++) {
    int e = hl[2 * k]; float dl = __int_as_float(hl[2 * k + 1]);
    int row = e & 63, d = e >> 8;
    int rl = row - rsub;
    if (rl >= 0 && rl < 32 && ((rl >> 2) & 3) == lq) {
      int i = rl >> 4, rr = rl & 3;
#pragma unroll
      for (int j = 0; j < 4; j++)
        acc[i][j][rr] += dl * W[(size_t)(cw + j * 16 + lm) * H_ + off + d];
    }
  }

  // base + store
  float* yb = y + (size_t)(n * L + r0 + rsub) * D_;
#pragma unroll
  for (int i = 0; i < 2; i++)
#pragma unroll
    for (int j = 0; j < 4; j++)
#pragma unroll
      for (int r = 0; r < 4; r++)
        yb[(size_t)(i * 16 + lq * 4 + r) * D_ + cw + j * 16 + lm] = acc[i][j][r] + bb[j];
}

extern "C" void kernel_launch(void* const* d_in, const int* in_sizes, int n_in,
                              void* d_out, int out_size, void* d_ws, size_t ws_size,
                              hipStream_t stream) {
  const float* x0 = (const float*)d_in[0];
  const float* x1 = (const float*)d_in[1];
  const float* W0 = (const float*)d_in[2];
  const float* b0 = (const float*)d_in[3];
  const float* W1 = (const float*)d_in[4];
  const float* b1 = (const float*)d_in[5];
  float* out = (float*)d_out;
  float* ws  = (float*)d_ws;

  hipLaunchKernelGGL(stats_kernel, dim3(768), dim3(256), 0, stream, x0, x1, ws);
  hipLaunchKernelGGL(prep_kernel,  dim3(32),  dim3(256), 0, stream, W0, b0, W1, b1, ws);
  hipLaunchKernelGGL(gemm_kernel,  dim3(768), dim3(256), 0, stream,
                     x0, x1, W0, W1, out, ws);
}